// Round 10
// baseline (721.633 us; speedup 1.0000x reference)
//
#include <hip/hip_runtime.h>
#include <stdint.h>

#define N_PTS 16384
#define TAU_C 0.001f
#define N_ITER 10

// ---- spatial grid over targets ----
#define G 48
#define NCELLS (G * G * G)              // 110592
#define XMIN (-6.0f)
#define CELL_H 0.25f
#define INV_H 4.0f
#define NSCAN ((NCELLS + 1023) / 1024)  // 108 scan blocks
#define GS 16                            // lanes cooperating per query
#define QPB (256 / GS)                   // 16 queries per block
#define NEVAL (N_PTS / QPB)              // 1024 eval blocks

struct State {
  float x[6];
  float xc[6];
  float dx[6];
  float Rc[9];
  float tc[3];
  float H[21];
  float g[6];
  float F, mu, nu;
};

// ---------------- se3 exp (matches reference formulas, fp32) ----------------
__device__ void se3_exp_rt(const float* x, float* R, float* t) {
  float wx = x[0], wy = x[1], wz = x[2];
  float vx = x[3], vy = x[4], vz = x[5];
  float th2 = wx*wx + wy*wy + wz*wz;
  float th = sqrtf(th2);
  float A, B, C;
  if (th < 1e-8f) {
    A = 1.0f - th2 / 6.0f;
    B = 0.5f - th2 / 24.0f;
    C = 1.0f / 6.0f - th2 / 120.0f;
  } else {
    float s = sinf(th), c = cosf(th);
    A = s / th;
    B = (1.0f - c) / th2;
    C = (th - s) / (th2 * th);
  }
  float W[9]  = {0.f, -wz, wy,  wz, 0.f, -wx,  -wy, wx, 0.f};
  float W2[9];
  #pragma unroll
  for (int r = 0; r < 3; r++)
    #pragma unroll
    for (int c = 0; c < 3; c++)
      W2[3*r+c] = W[3*r+0]*W[0+c] + W[3*r+1]*W[3+c] + W[3*r+2]*W[6+c];
  float V[9];
  #pragma unroll
  for (int k = 0; k < 9; k++) {
    float I = (k == 0 || k == 4 || k == 8) ? 1.f : 0.f;
    R[k] = I + A * W[k] + B * W2[k];
    V[k] = I + B * W[k] + C * W2[k];
  }
  t[0] = V[0]*vx + V[1]*vy + V[2]*vz;
  t[1] = V[3]*vx + V[4]*vy + V[5]*vz;
  t[2] = V[6]*vx + V[7]*vy + V[8]*vz;
}

__device__ inline int cell1d(float v) {
  int c = (int)floorf((v - XMIN) * INV_H);
  return min(max(c, 0), G - 1);
}

// ---------------- prep 1: zero counts, init counter + state ----------------
__global__ __launch_bounds__(256) void zero_kernel(unsigned* __restrict__ count,
                                                   unsigned* __restrict__ counter,
                                                   State* st) {
  unsigned idx = blockIdx.x * 256u + threadIdx.x;
  if (idx < NCELLS) count[idx] = 0u;
  if (idx == 0) {
    #pragma unroll
    for (int k = 0; k < 6; k++) { st->x[k] = 0.f; st->xc[k] = 0.f; st->dx[k] = 0.f; }
    #pragma unroll
    for (int k = 0; k < 9; k++) st->Rc[k] = (k % 4 == 0) ? 1.f : 0.f;
    st->tc[0] = st->tc[1] = st->tc[2] = 0.f;
    st->nu = 2.f;
    *counter = 0u;
  }
}

// ---------------- prep 2: histogram targets into cells ----------------
__global__ __launch_bounds__(256) void count_kernel(const float* __restrict__ trg,
                                                    unsigned* __restrict__ count) {
  int j = blockIdx.x * 256 + threadIdx.x;
  int cx = cell1d(trg[3*j]), cy = cell1d(trg[3*j+1]), cz = cell1d(trg[3*j+2]);
  atomicAdd(&count[(cz * G + cy) * G + cx], 1u);
}

// ---------------- prep 3: block-local exclusive scan (1024 items/block) ----------------
__global__ __launch_bounds__(256) void scan1_kernel(const unsigned* __restrict__ count,
                                                    unsigned* __restrict__ excl,
                                                    unsigned* __restrict__ blockSums) {
  __shared__ unsigned sh[256];
  const int t = threadIdx.x;
  const unsigned base = blockIdx.x * 1024u + t * 4u;
  unsigned v0 = (base + 0 < NCELLS) ? count[base + 0] : 0u;
  unsigned v1 = (base + 1 < NCELLS) ? count[base + 1] : 0u;
  unsigned v2 = (base + 2 < NCELLS) ? count[base + 2] : 0u;
  unsigned v3 = (base + 3 < NCELLS) ? count[base + 3] : 0u;
  unsigned tsum = v0 + v1 + v2 + v3;
  sh[t] = tsum;
  __syncthreads();
  for (int off = 1; off < 256; off <<= 1) {
    unsigned xv = (t >= off) ? sh[t - off] : 0u;
    __syncthreads();
    sh[t] += xv;
    __syncthreads();
  }
  unsigned texcl = sh[t] - tsum;
  if (t == 255) blockSums[blockIdx.x] = sh[255];
  if (base + 0 < NCELLS) excl[base + 0] = texcl;
  if (base + 1 < NCELLS) excl[base + 1] = texcl + v0;
  if (base + 2 < NCELLS) excl[base + 2] = texcl + v0 + v1;
  if (base + 3 < NCELLS) excl[base + 3] = texcl + v0 + v1 + v2;
}

// ---------------- prep 4: scan block sums (single block) ----------------
__global__ __launch_bounds__(512) void scan2_kernel(unsigned* __restrict__ blockSums) {
  __shared__ unsigned sh[512];
  int t = threadIdx.x;
  unsigned v = (t < NSCAN) ? blockSums[t] : 0u;
  sh[t] = v;
  __syncthreads();
  for (int off = 1; off < 512; off <<= 1) {
    unsigned xv = (t >= off) ? sh[t - off] : 0u;
    __syncthreads();
    sh[t] += xv;
    __syncthreads();
  }
  if (t < NSCAN) blockSums[t] = sh[t] - v;   // exclusive
}

// ---------------- prep 5: finalize starts; pack (start<<8 | count) ----------------
__global__ __launch_bounds__(256) void scan3_kernel(const unsigned* __restrict__ count,
                                                    unsigned* __restrict__ cursor,
                                                    const unsigned* __restrict__ blockSums,
                                                    unsigned* __restrict__ gridPacked) {
  const unsigned base = blockIdx.x * 1024u + threadIdx.x * 4u;
  unsigned boff = blockSums[blockIdx.x];
  #pragma unroll
  for (int q = 0; q < 4; q++) {
    unsigned idx = base + q;
    if (idx < NCELLS) {
      unsigned start = cursor[idx] + boff;
      unsigned n = count[idx]; n = n > 255u ? 255u : n;
      gridPacked[idx] = (start << 8) | n;
      cursor[idx] = start;
    }
  }
}

// ---------------- prep 6: scatter targets into sorted order ----------------
__global__ __launch_bounds__(256) void scatter_kernel(const float* __restrict__ trg,
                                                      unsigned* __restrict__ cursor,
                                                      float4* __restrict__ sortedPts,
                                                      unsigned* __restrict__ sortedIdx) {
  int j = blockIdx.x * 256 + threadIdx.x;
  float tx = trg[3*j], ty = trg[3*j+1], tz = trg[3*j+2];
  int cx = cell1d(tx), cy = cell1d(ty), cz = cell1d(tz);
  unsigned pos = atomicAdd(&cursor[(cz * G + cy) * G + cx], 1u);
  sortedPts[pos] = make_float4(tx, ty, tz, __uint_as_float((unsigned)j));
  sortedIdx[pos] = (unsigned)j;
}

// ======== fused eval: 2-tier exact NN + accumulate + last-block LM ========
// Tier 1: 27-cell box, 16 lanes/query, exact face-bound stop test.
// Tier 2: unresolved groups -> whole-wave brute force over sortedPts.
// Both tiers: same d2 formula, key=(d2bits<<32|j) -> exact smallest-j
// tie-break (== jnp.argmin). d2>=0 so uint order == float order.
__global__ __launch_bounds__(256) void eval_kernel(const float* __restrict__ ref,
                                                   const float* __restrict__ trg,
                                                   const float* __restrict__ nrm,
                                                   const unsigned* __restrict__ gridPacked,
                                                   const float4* __restrict__ sortedPts,
                                                   const unsigned* __restrict__ sortedIdx,
                                                   State* st,
                                                   double* __restrict__ partials,
                                                   unsigned* __restrict__ counter,
                                                   float* out, int mode) {
  const int tid = threadIdx.x;
  const int lane = tid & 63;
  const int gl = tid & (GS - 1);
  const int it = blockIdx.x * QPB + (tid >> 4);
  const int i = (int)sortedIdx[it];          // spatially-sorted query order

  const float R00 = st->Rc[0], R01 = st->Rc[1], R02 = st->Rc[2];
  const float R10 = st->Rc[3], R11 = st->Rc[4], R12 = st->Rc[5];
  const float R20 = st->Rc[6], R21 = st->Rc[7], R22 = st->Rc[8];
  const float t0 = st->tc[0], t1 = st->tc[1], t2 = st->tc[2];

  const float rx = ref[3*i], ry = ref[3*i+1], rz = ref[3*i+2];
  const float ax = rx - t0, ay = ry - t1, az = rz - t2;
  const float qx = R00*ax + R10*ay + R20*az;
  const float qy = R01*ax + R11*ay + R21*az;
  const float qz = R02*ax + R12*ay + R22*az;
  const int gx = cell1d(qx), gy = cell1d(qy), gz = cell1d(qz);

  // ---- tier 1: 27-cell box; hoisted descriptor loads (2/lane, parallel) ----
  unsigned pcv[2];
  #pragma unroll
  for (int k = 0; k < 2; k++) {
    pcv[k] = 0u;
    int t = gl + GS * k;
    if (t < 27) {
      int tz = t / 9, rm = t - tz * 9, ty = rm / 3, tx = rm - ty * 3;
      int cz = gz + tz - 1, cy = gy + ty - 1, cx = gx + tx - 1;
      if ((unsigned)cx < (unsigned)G && (unsigned)cy < (unsigned)G &&
          (unsigned)cz < (unsigned)G)
        pcv[k] = gridPacked[(cz * G + cy) * G + cx];
    }
  }
  unsigned long long bkey = 0xFFFFFFFFFFFFFFFFULL;
  #pragma unroll
  for (int k = 0; k < 2; k++) {
    unsigned s0 = pcv[k] >> 8, n = pcv[k] & 255u;
    for (unsigned c = 0; c < n; c++) {
      float4 p = sortedPts[s0 + c];
      float ddx = qx - p.x, ddy = qy - p.y, ddz = qz - p.z;
      float d2 = fmaf(ddz, ddz, fmaf(ddy, ddy, ddx * ddx));
      unsigned long long key = ((unsigned long long)__float_as_uint(d2) << 32)
                             | (unsigned long long)(unsigned)__float_as_uint(p.w);
      bkey = key < bkey ? key : bkey;
    }
  }
  // group min across 16 cooperating lanes
  #pragma unroll
  for (int off = 1; off < GS; off <<= 1) {
    unsigned long long o = __shfl_xor(bkey, off, 64);
    bkey = o < bkey ? o : bkey;
  }
  float best = __uint_as_float((unsigned)(bkey >> 32));  // NaN if box empty
  // distance to nearest unscanned face (grid-edge faces excluded: clamped
  // points live in edge cells, which the box covers)
  float dmin = 3.4e38f;
  if (gx - 1 > 0)     dmin = fminf(dmin, qx - (XMIN + (float)(gx - 1) * CELL_H));
  if (gx + 1 < G - 1) dmin = fminf(dmin, (XMIN + (float)(gx + 2) * CELL_H) - qx);
  if (gy - 1 > 0)     dmin = fminf(dmin, qy - (XMIN + (float)(gy - 1) * CELL_H));
  if (gy + 1 < G - 1) dmin = fminf(dmin, (XMIN + (float)(gy + 2) * CELL_H) - qy);
  if (gz - 1 > 0)     dmin = fminf(dmin, qz - (XMIN + (float)(gz - 1) * CELL_H));
  if (gz + 1 < G - 1) dmin = fminf(dmin, (XMIN + (float)(gz + 2) * CELL_H) - qz);
  bool resolved = (best <= dmin * dmin);   // NaN -> false -> brute

  // ---- tier 2: wave-cooperative brute force for unresolved groups ----
  unsigned long long m = __ballot((gl == 0) && !resolved);
  while (m) {
    int src = __ffsll((long long)m) - 1;
    m &= m - 1;
    float bqx = __shfl(qx, src, 64);
    float bqy = __shfl(qy, src, 64);
    float bqz = __shfl(qz, src, 64);
    unsigned long long bb = 0xFFFFFFFFFFFFFFFFULL;
    #pragma unroll 4
    for (int p = lane; p < N_PTS; p += 64) {
      float4 pt = sortedPts[p];
      float ddx = bqx - pt.x, ddy = bqy - pt.y, ddz = bqz - pt.z;
      float d2 = fmaf(ddz, ddz, fmaf(ddy, ddy, ddx * ddx));
      unsigned long long key = ((unsigned long long)__float_as_uint(d2) << 32)
                             | (unsigned long long)(unsigned)__float_as_uint(pt.w);
      bb = key < bb ? key : bb;
    }
    #pragma unroll
    for (int off = 1; off < 64; off <<= 1) {
      unsigned long long o = __shfl_xor(bb, off, 64);
      bb = o < bb ? o : bb;
    }
    if ((lane >> 4) == (src >> 4)) bkey = bb;   // hand result to src's group
  }
  const int j = (int)(unsigned)(bkey & 0xFFFFFFFFULL);

  // ---- point-to-plane residual + Jacobian (group leader only; others zero) ----
  float Jv[6] = {0.f, 0.f, 0.f, 0.f, 0.f, 0.f};
  float rres = 0.f;
  if (gl == 0) {
    float nx0 = nrm[3*j], ny0 = nrm[3*j+1], nz0 = nrm[3*j+2];
    float sx = trg[3*j], sy = trg[3*j+1], sz = trg[3*j+2];
    float nx = R00*nx0 + R01*ny0 + R02*nz0;
    float ny = R10*nx0 + R11*ny0 + R12*nz0;
    float nz = R20*nx0 + R21*ny0 + R22*nz0;
    float pxx = R00*sx + R01*sy + R02*sz + t0;
    float pyy = R10*sx + R11*sy + R12*sz + t1;
    float pzz = R20*sx + R21*sy + R22*sz + t2;
    float dxx = rx - pxx, dyy = ry - pyy, dzz = rz - pzz;
    rres = nx*dxx + ny*dyy + nz*dzz;
    Jv[0] = ry*nz - rz*ny;
    Jv[1] = rz*nx - rx*nz;
    Jv[2] = rx*ny - ry*nx;
    Jv[3] = nx; Jv[4] = ny; Jv[5] = nz;
  }

  // double accumulation -> insensitive to scatter-order permutation.
  // nonzero only on lanes 0,16,32,48 -> 2-round leader reduce to lane 0.
  double acc[28];
  int c21 = 0;
  #pragma unroll
  for (int a = 0; a < 6; a++)
    #pragma unroll
    for (int b = a; b < 6; b++)
      acc[c21++] = (double)Jv[a] * (double)Jv[b];
  #pragma unroll
  for (int a = 0; a < 6; a++) acc[21+a] = (double)Jv[a] * (double)rres;
  acc[27] = (double)rres * (double)rres;

  #pragma unroll
  for (int kk = 0; kk < 28; kk++) {
    double v = acc[kk];
    v += __shfl_down(v, 16, 64);
    v += __shfl_down(v, 32, 64);
    acc[kk] = v;
  }
  __shared__ double redD[4][28];
  int wave = tid >> 6;
  if (lane == 0) {
    #pragma unroll
    for (int kk = 0; kk < 28; kk++) redD[wave][kk] = acc[kk];
  }
  __syncthreads();
  if (tid < 28)
    partials[tid * NEVAL + blockIdx.x] =
        redD[0][tid] + redD[1][tid] + redD[2][tid] + redD[3][tid];

  // ---- last-block-does-LM ----
  __shared__ bool last;
  __syncthreads();
  if (tid == 0) {
    __threadfence();
    unsigned old = atomicAdd(counter, 1u);
    last = (old == NEVAL - 1);
  }
  __syncthreads();
  if (!last) return;

  __threadfence();
  // fixed-order two-stage sum over 1024 blocks (deterministic, 4-way unrolled)
  __shared__ double red2[28][8];
  if (tid < 224) {
    int c = tid >> 3, s = tid & 7;
    const double* pp = partials + c * NEVAL + s * 128;
    double s0 = 0.0, s1 = 0.0, s2 = 0.0, s3 = 0.0;
    for (int b = 0; b < 128; b += 4) {
      s0 += pp[b]; s1 += pp[b+1]; s2 += pp[b+2]; s3 += pp[b+3];
    }
    red2[c][s] = (s0 + s1) + (s2 + s3);
  }
  __syncthreads();
  __shared__ float tot[28];
  if (tid < 28) {
    double s = 0.0;
    #pragma unroll
    for (int k = 0; k < 8; k++) s += red2[tid][k];
    tot[tid] = (float)s;
  }
  __syncthreads();

  if (tid == 0) {
    atomicExch(counter, 0u);           // reset for next eval
    float Fn = tot[27];
    float mu, nu;

    if (mode == 0) {
      #pragma unroll
      for (int k = 0; k < 6; k++) st->x[k] = st->xc[k];
      #pragma unroll
      for (int k = 0; k < 21; k++) st->H[k] = tot[k];
      #pragma unroll
      for (int k = 0; k < 6; k++) st->g[k] = tot[21+k];
      st->F = Fn;
      float md = tot[0];
      md = fmaxf(md, tot[6]); md = fmaxf(md, tot[11]); md = fmaxf(md, tot[15]);
      md = fmaxf(md, tot[18]); md = fmaxf(md, tot[20]);
      mu = TAU_C * md;
      nu = 2.f;
    } else {
      mu = st->mu; nu = st->nu;
      float denom = 0.f;
      #pragma unroll
      for (int k = 0; k < 6; k++) denom += st->dx[k] * (mu * st->dx[k] - st->g[k]);
      if (fabsf(denom) < 1e-12f) denom = 1e-12f;
      float rho = (st->F - Fn) / denom;
      if (rho > 0.f) {
        #pragma unroll
        for (int k = 0; k < 6; k++) st->x[k] = st->xc[k];
        #pragma unroll
        for (int k = 0; k < 21; k++) st->H[k] = tot[k];
        #pragma unroll
        for (int k = 0; k < 6; k++) st->g[k] = tot[21+k];
        st->F = Fn;
        float tcube = 2.f * rho - 1.f;
        mu = mu * fmaxf(1.f / 3.f, 1.f - tcube * tcube * tcube);
        nu = 2.f;
      } else {
        mu = mu * nu;
        nu = 2.f * nu;
      }
    }
    st->mu = mu; st->nu = nu;

    if (mode < N_ITER) {
      // solve (H + mu I) d = -g ; SPD -> unpivoted Gauss, fully unrolled
      float A[6][7];
      int c21b = 0;
      #pragma unroll
      for (int a = 0; a < 6; a++)
        #pragma unroll
        for (int b = a; b < 6; b++) { A[a][b] = st->H[c21b]; A[b][a] = st->H[c21b]; c21b++; }
      #pragma unroll
      for (int a = 0; a < 6; a++) { A[a][a] += mu; A[a][6] = -st->g[a]; }
      #pragma unroll
      for (int col = 0; col < 6; col++) {
        float inv = 1.f / A[col][col];
        #pragma unroll
        for (int rI = 0; rI < 6; rI++) {
          if (rI > col) {
            float f = A[rI][col] * inv;
            #pragma unroll
            for (int cc = 0; cc < 7; cc++)
              if (cc >= col) A[rI][cc] -= f * A[col][cc];
          }
        }
      }
      float d[6];
      #pragma unroll
      for (int rI = 5; rI >= 0; rI--) {
        float s = A[rI][6];
        #pragma unroll
        for (int cc = 0; cc < 6; cc++)
          if (cc > rI) s -= A[rI][cc] * d[cc];
        d[rI] = s / A[rI][rI];
      }
      float Rn[9], tn[3];
      #pragma unroll
      for (int k = 0; k < 6; k++) { st->dx[k] = d[k]; st->xc[k] = st->x[k] + d[k]; }
      se3_exp_rt(st->xc, Rn, tn);
      #pragma unroll
      for (int k = 0; k < 9; k++) st->Rc[k] = Rn[k];
      #pragma unroll
      for (int k = 0; k < 3; k++) st->tc[k] = tn[k];
    } else {
      float Rn[9], tn[3];
      se3_exp_rt(st->x, Rn, tn);
      out[0] = Rn[0]; out[1] = Rn[1]; out[2]  = Rn[2]; out[3]  = tn[0];
      out[4] = Rn[3]; out[5] = Rn[4]; out[6]  = Rn[5]; out[7]  = tn[1];
      out[8] = Rn[6]; out[9] = Rn[7]; out[10] = Rn[8]; out[11] = tn[2];
      out[12] = 0.f; out[13] = 0.f; out[14] = 0.f; out[15] = 1.f;
      out[16] = st->F / (float)N_PTS;
    }
  }
}

extern "C" void kernel_launch(void* const* d_in, const int* in_sizes, int n_in,
                              void* d_out, int out_size, void* d_ws, size_t ws_size,
                              hipStream_t stream) {
  const float* ref = (const float*)d_in[0];
  const float* trg = (const float*)d_in[1];
  const float* nrm = (const float*)d_in[2];
  float* out = (float*)d_out;

  char* ws = (char*)d_ws;
  unsigned* count      = (unsigned*)(ws);                       // 442,368 B
  unsigned* gridPacked = (unsigned*)(ws + 442368);              // 442,368 B
  unsigned* cursor     = (unsigned*)(ws + 884736);              // 442,368 B
  unsigned* blockSums  = (unsigned*)(ws + 1327104);             // 2,048 B
  float4*   sortedPts  = (float4*)  (ws + 1329152);             // 262,144 B
  unsigned* sortedIdx  = (unsigned*)(ws + 1591296);             // 65,536 B
  double*   partials   = (double*)  (ws + 1656832);             // 229,376 B
  unsigned* counter    = (unsigned*)(ws + 1886208);
  State*    st         = (State*)   (ws + 1886272);

  // build grid over targets (once) + init LM state
  zero_kernel   <<<(NCELLS + 255) / 256, 256, 0, stream>>>(count, counter, st);
  count_kernel  <<<N_PTS / 256, 256, 0, stream>>>(trg, count);
  scan1_kernel  <<<NSCAN, 256, 0, stream>>>(count, cursor, blockSums);
  scan2_kernel  <<<1, 512, 0, stream>>>(blockSums);
  scan3_kernel  <<<NSCAN, 256, 0, stream>>>(count, cursor, blockSums, gridPacked);
  scatter_kernel<<<N_PTS / 256, 256, 0, stream>>>(trg, cursor, sortedPts, sortedIdx);

  for (int e = 0; e <= N_ITER; e++)
    eval_kernel<<<NEVAL, 256, 0, stream>>>(ref, trg, nrm, gridPacked, sortedPts,
                                           sortedIdx, st, partials, counter, out, e);
}

// Round 11
// 520.429 us; speedup vs baseline: 1.3866x; 1.3866x over previous
//
#include <hip/hip_runtime.h>
#include <stdint.h>

#define N_PTS 16384
#define TAU_C 0.001f
#define N_ITER 10

// ---- spatial grid over targets ----
#define G 48
#define NCELLS (G * G * G)              // 110592
#define XMIN (-6.0f)
#define CELL_H 0.25f
#define INV_H 4.0f
#define NSCAN ((NCELLS + 1023) / 1024)  // 108 scan blocks
#define GS 16                            // lanes cooperating per query
#define QPB (256 / GS)                   // 16 queries per block
#define NEVAL (N_PTS / QPB)              // 1024 eval blocks

struct State {
  float x[6];
  float xc[6];
  float dx[6];
  float Rc[9];
  float tc[3];
  float H[21];
  float g[6];
  float F, mu, nu;
};

// ---------------- se3 exp (matches reference formulas, fp32) ----------------
__device__ void se3_exp_rt(const float* x, float* R, float* t) {
  float wx = x[0], wy = x[1], wz = x[2];
  float vx = x[3], vy = x[4], vz = x[5];
  float th2 = wx*wx + wy*wy + wz*wz;
  float th = sqrtf(th2);
  float A, B, C;
  if (th < 1e-8f) {
    A = 1.0f - th2 / 6.0f;
    B = 0.5f - th2 / 24.0f;
    C = 1.0f / 6.0f - th2 / 120.0f;
  } else {
    float s = sinf(th), c = cosf(th);
    A = s / th;
    B = (1.0f - c) / th2;
    C = (th - s) / (th2 * th);
  }
  float W[9]  = {0.f, -wz, wy,  wz, 0.f, -wx,  -wy, wx, 0.f};
  float W2[9];
  #pragma unroll
  for (int r = 0; r < 3; r++)
    #pragma unroll
    for (int c = 0; c < 3; c++)
      W2[3*r+c] = W[3*r+0]*W[0+c] + W[3*r+1]*W[3+c] + W[3*r+2]*W[6+c];
  float V[9];
  #pragma unroll
  for (int k = 0; k < 9; k++) {
    float I = (k == 0 || k == 4 || k == 8) ? 1.f : 0.f;
    R[k] = I + A * W[k] + B * W2[k];
    V[k] = I + B * W[k] + C * W2[k];
  }
  t[0] = V[0]*vx + V[1]*vy + V[2]*vz;
  t[1] = V[3]*vx + V[4]*vy + V[5]*vz;
  t[2] = V[6]*vx + V[7]*vy + V[8]*vz;
}

__device__ inline int cell1d(float v) {
  int c = (int)floorf((v - XMIN) * INV_H);
  return min(max(c, 0), G - 1);
}

// ---------------- prep 1: zero counts, init counter + state ----------------
__global__ __launch_bounds__(256) void zero_kernel(unsigned* __restrict__ count,
                                                   unsigned* __restrict__ counter,
                                                   State* st) {
  unsigned idx = blockIdx.x * 256u + threadIdx.x;
  if (idx < NCELLS) count[idx] = 0u;
  if (idx == 0) {
    #pragma unroll
    for (int k = 0; k < 6; k++) { st->x[k] = 0.f; st->xc[k] = 0.f; st->dx[k] = 0.f; }
    #pragma unroll
    for (int k = 0; k < 9; k++) st->Rc[k] = (k % 4 == 0) ? 1.f : 0.f;
    st->tc[0] = st->tc[1] = st->tc[2] = 0.f;
    st->nu = 2.f;
    *counter = 0u;
  }
}

// ---------------- prep 2: histogram targets into cells ----------------
__global__ __launch_bounds__(256) void count_kernel(const float* __restrict__ trg,
                                                    unsigned* __restrict__ count) {
  int j = blockIdx.x * 256 + threadIdx.x;
  int cx = cell1d(trg[3*j]), cy = cell1d(trg[3*j+1]), cz = cell1d(trg[3*j+2]);
  atomicAdd(&count[(cz * G + cy) * G + cx], 1u);
}

// ---------------- prep 3: block-local exclusive scan (1024 items/block) ----------------
__global__ __launch_bounds__(256) void scan1_kernel(const unsigned* __restrict__ count,
                                                    unsigned* __restrict__ excl,
                                                    unsigned* __restrict__ blockSums) {
  __shared__ unsigned sh[256];
  const int t = threadIdx.x;
  const unsigned base = blockIdx.x * 1024u + t * 4u;
  unsigned v0 = (base + 0 < NCELLS) ? count[base + 0] : 0u;
  unsigned v1 = (base + 1 < NCELLS) ? count[base + 1] : 0u;
  unsigned v2 = (base + 2 < NCELLS) ? count[base + 2] : 0u;
  unsigned v3 = (base + 3 < NCELLS) ? count[base + 3] : 0u;
  unsigned tsum = v0 + v1 + v2 + v3;
  sh[t] = tsum;
  __syncthreads();
  for (int off = 1; off < 256; off <<= 1) {
    unsigned xv = (t >= off) ? sh[t - off] : 0u;
    __syncthreads();
    sh[t] += xv;
    __syncthreads();
  }
  unsigned texcl = sh[t] - tsum;
  if (t == 255) blockSums[blockIdx.x] = sh[255];
  if (base + 0 < NCELLS) excl[base + 0] = texcl;
  if (base + 1 < NCELLS) excl[base + 1] = texcl + v0;
  if (base + 2 < NCELLS) excl[base + 2] = texcl + v0 + v1;
  if (base + 3 < NCELLS) excl[base + 3] = texcl + v0 + v1 + v2;
}

// ---------------- prep 4: scan block sums (single block) ----------------
__global__ __launch_bounds__(512) void scan2_kernel(unsigned* __restrict__ blockSums) {
  __shared__ unsigned sh[512];
  int t = threadIdx.x;
  unsigned v = (t < NSCAN) ? blockSums[t] : 0u;
  sh[t] = v;
  __syncthreads();
  for (int off = 1; off < 512; off <<= 1) {
    unsigned xv = (t >= off) ? sh[t - off] : 0u;
    __syncthreads();
    sh[t] += xv;
    __syncthreads();
  }
  if (t < NSCAN) blockSums[t] = sh[t] - v;   // exclusive
}

// ---------------- prep 5: finalize starts; pack (start<<8 | count) ----------------
__global__ __launch_bounds__(256) void scan3_kernel(const unsigned* __restrict__ count,
                                                    unsigned* __restrict__ cursor,
                                                    const unsigned* __restrict__ blockSums,
                                                    unsigned* __restrict__ gridPacked) {
  const unsigned base = blockIdx.x * 1024u + threadIdx.x * 4u;
  unsigned boff = blockSums[blockIdx.x];
  #pragma unroll
  for (int q = 0; q < 4; q++) {
    unsigned idx = base + q;
    if (idx < NCELLS) {
      unsigned start = cursor[idx] + boff;
      unsigned n = count[idx]; n = n > 255u ? 255u : n;
      gridPacked[idx] = (start << 8) | n;
      cursor[idx] = start;
    }
  }
}

// ---------------- prep 6: scatter targets into sorted order ----------------
__global__ __launch_bounds__(256) void scatter_kernel(const float* __restrict__ trg,
                                                      unsigned* __restrict__ cursor,
                                                      float4* __restrict__ sortedPts,
                                                      unsigned* __restrict__ sortedIdx) {
  int j = blockIdx.x * 256 + threadIdx.x;
  float tx = trg[3*j], ty = trg[3*j+1], tz = trg[3*j+2];
  int cx = cell1d(tx), cy = cell1d(ty), cz = cell1d(tz);
  unsigned pos = atomicAdd(&cursor[(cz * G + cy) * G + cx], 1u);
  sortedPts[pos] = make_float4(tx, ty, tz, __uint_as_float((unsigned)j));
  sortedIdx[pos] = (unsigned)j;
}

// ======== fused eval: bounded-ball exact NN + accumulate + last-block LM ========
// Exact NN in ONE pass: the partner target trg[i] gives an O(1) upper bound
// d_ub >= NN distance (trg = R_true*ref + t_true). Scan every cell
// intersecting [q +- d_ub]^3 (clamped; edge cells hold clamped points, so
// coverage is guaranteed). d_ub inflated by 4e-6 rel to cover fp rounding ->
// the scanned set provably contains the argmin and all its ties.
// key=(d2bits<<32|j) -> exact smallest-j tie-break (== jnp.argmin).
__global__ __launch_bounds__(256) void eval_kernel(const float* __restrict__ ref,
                                                   const float* __restrict__ trg,
                                                   const float* __restrict__ nrm,
                                                   const unsigned* __restrict__ gridPacked,
                                                   const float4* __restrict__ sortedPts,
                                                   const unsigned* __restrict__ sortedIdx,
                                                   State* st,
                                                   double* __restrict__ partials,
                                                   unsigned* __restrict__ counter,
                                                   float* out, int mode) {
  const int tid = threadIdx.x;
  const int lane = tid & 63;
  const int gl = tid & (GS - 1);
  const int it = blockIdx.x * QPB + (tid >> 4);
  const int i = (int)sortedIdx[it];          // spatially-sorted query order

  const float R00 = st->Rc[0], R01 = st->Rc[1], R02 = st->Rc[2];
  const float R10 = st->Rc[3], R11 = st->Rc[4], R12 = st->Rc[5];
  const float R20 = st->Rc[6], R21 = st->Rc[7], R22 = st->Rc[8];
  const float t0 = st->tc[0], t1 = st->tc[1], t2 = st->tc[2];

  const float rx = ref[3*i], ry = ref[3*i+1], rz = ref[3*i+2];
  const float ax = rx - t0, ay = ry - t1, az = rz - t2;
  const float qx = R00*ax + R10*ay + R20*az;
  const float qy = R01*ax + R11*ay + R21*az;
  const float qz = R02*ax + R12*ay + R22*az;

  // O(1) upper bound on NN distance: distance to partner trg[i]
  const float wx_ = trg[3*i], wy_ = trg[3*i+1], wz_ = trg[3*i+2];
  float dpx = qx - wx_, dpy = qy - wy_, dpz = qz - wz_;
  float dub = sqrtf(fmaf(dpz, dpz, fmaf(dpy, dpy, dpx * dpx)));
  dub = fmaf(dub, 4e-6f, dub) + 2e-7f;   // fp-safety inflation

  const int lox = cell1d(qx - dub), hix = cell1d(qx + dub);
  const int loy = cell1d(qy - dub), hiy = cell1d(qy + dub);
  const int loz = cell1d(qz - dub), hiz = cell1d(qz + dub);
  const int nx_ = hix - lox + 1, ny_ = hiy - loy + 1, nz_ = hiz - loz + 1;
  const int nxy = nx_ * ny_, nc = nxy * nz_;

  unsigned long long bkey = 0xFFFFFFFFFFFFFFFFULL;
  for (int t = gl; t < nc; t += GS) {
    int tz = t / nxy;
    int rm = t - tz * nxy;
    int ty = rm / nx_;
    int tx = rm - ty * nx_;
    unsigned pc = gridPacked[((loz + tz) * G + (loy + ty)) * G + (lox + tx)];
    unsigned s0 = pc >> 8, n = pc & 255u;
    for (unsigned c = 0; c < n; c++) {
      float4 p = sortedPts[s0 + c];
      float ddx = qx - p.x, ddy = qy - p.y, ddz = qz - p.z;
      float d2 = fmaf(ddz, ddz, fmaf(ddy, ddy, ddx * ddx));
      unsigned long long key = ((unsigned long long)__float_as_uint(d2) << 32)
                             | (unsigned long long)(unsigned)__float_as_uint(p.w);
      bkey = key < bkey ? key : bkey;
    }
  }
  // group min across 16 cooperating lanes
  #pragma unroll
  for (int off = 1; off < GS; off <<= 1) {
    unsigned long long o = __shfl_xor(bkey, off, 64);
    bkey = o < bkey ? o : bkey;
  }
  const int j = (int)(unsigned)(bkey & 0xFFFFFFFFULL);

  // ---- point-to-plane residual + Jacobian (group leader only; others zero) ----
  float Jv[6] = {0.f, 0.f, 0.f, 0.f, 0.f, 0.f};
  float rres = 0.f;
  if (gl == 0) {
    float nx0 = nrm[3*j], ny0 = nrm[3*j+1], nz0 = nrm[3*j+2];
    float sx = trg[3*j], sy = trg[3*j+1], sz = trg[3*j+2];
    float nx = R00*nx0 + R01*ny0 + R02*nz0;
    float ny = R10*nx0 + R11*ny0 + R12*nz0;
    float nz = R20*nx0 + R21*ny0 + R22*nz0;
    float pxx = R00*sx + R01*sy + R02*sz + t0;
    float pyy = R10*sx + R11*sy + R12*sz + t1;
    float pzz = R20*sx + R21*sy + R22*sz + t2;
    float dxx = rx - pxx, dyy = ry - pyy, dzz = rz - pzz;
    rres = nx*dxx + ny*dyy + nz*dzz;
    Jv[0] = ry*nz - rz*ny;
    Jv[1] = rz*nx - rx*nz;
    Jv[2] = rx*ny - ry*nx;
    Jv[3] = nx; Jv[4] = ny; Jv[5] = nz;
  }

  // double accumulation -> insensitive to scatter-order permutation.
  // nonzero only on lanes 0,16,32,48 -> 2-round leader reduce to lane 0.
  double acc[28];
  int c21 = 0;
  #pragma unroll
  for (int a = 0; a < 6; a++)
    #pragma unroll
    for (int b = a; b < 6; b++)
      acc[c21++] = (double)Jv[a] * (double)Jv[b];
  #pragma unroll
  for (int a = 0; a < 6; a++) acc[21+a] = (double)Jv[a] * (double)rres;
  acc[27] = (double)rres * (double)rres;

  #pragma unroll
  for (int kk = 0; kk < 28; kk++) {
    double v = acc[kk];
    v += __shfl_down(v, 16, 64);
    v += __shfl_down(v, 32, 64);
    acc[kk] = v;
  }
  __shared__ double redD[4][28];
  int wave = tid >> 6;
  if (lane == 0) {
    #pragma unroll
    for (int kk = 0; kk < 28; kk++) redD[wave][kk] = acc[kk];
  }
  __syncthreads();
  if (tid < 28)
    partials[tid * NEVAL + blockIdx.x] =
        redD[0][tid] + redD[1][tid] + redD[2][tid] + redD[3][tid];

  // ---- last-block-does-LM ----
  __shared__ bool last;
  __syncthreads();
  if (tid == 0) {
    __threadfence();
    unsigned old = atomicAdd(counter, 1u);
    last = (old == NEVAL - 1);
  }
  __syncthreads();
  if (!last) return;

  __threadfence();
  // fixed-order two-stage sum over 1024 blocks (deterministic, 4-way unrolled)
  __shared__ double red2[28][8];
  if (tid < 224) {
    int c = tid >> 3, s = tid & 7;
    const double* pp = partials + c * NEVAL + s * 128;
    double s0 = 0.0, s1 = 0.0, s2 = 0.0, s3 = 0.0;
    for (int b = 0; b < 128; b += 4) {
      s0 += pp[b]; s1 += pp[b+1]; s2 += pp[b+2]; s3 += pp[b+3];
    }
    red2[c][s] = (s0 + s1) + (s2 + s3);
  }
  __syncthreads();
  __shared__ float tot[28];
  if (tid < 28) {
    double s = 0.0;
    #pragma unroll
    for (int k = 0; k < 8; k++) s += red2[tid][k];
    tot[tid] = (float)s;
  }
  __syncthreads();

  if (tid == 0) {
    atomicExch(counter, 0u);           // reset for next eval
    float Fn = tot[27];
    float mu, nu;

    if (mode == 0) {
      #pragma unroll
      for (int k = 0; k < 6; k++) st->x[k] = st->xc[k];
      #pragma unroll
      for (int k = 0; k < 21; k++) st->H[k] = tot[k];
      #pragma unroll
      for (int k = 0; k < 6; k++) st->g[k] = tot[21+k];
      st->F = Fn;
      float md = tot[0];
      md = fmaxf(md, tot[6]); md = fmaxf(md, tot[11]); md = fmaxf(md, tot[15]);
      md = fmaxf(md, tot[18]); md = fmaxf(md, tot[20]);
      mu = TAU_C * md;
      nu = 2.f;
    } else {
      mu = st->mu; nu = st->nu;
      float denom = 0.f;
      #pragma unroll
      for (int k = 0; k < 6; k++) denom += st->dx[k] * (mu * st->dx[k] - st->g[k]);
      if (fabsf(denom) < 1e-12f) denom = 1e-12f;
      float rho = (st->F - Fn) / denom;
      if (rho > 0.f) {
        #pragma unroll
        for (int k = 0; k < 6; k++) st->x[k] = st->xc[k];
        #pragma unroll
        for (int k = 0; k < 21; k++) st->H[k] = tot[k];
        #pragma unroll
        for (int k = 0; k < 6; k++) st->g[k] = tot[21+k];
        st->F = Fn;
        float tcube = 2.f * rho - 1.f;
        mu = mu * fmaxf(1.f / 3.f, 1.f - tcube * tcube * tcube);
        nu = 2.f;
      } else {
        mu = mu * nu;
        nu = 2.f * nu;
      }
    }
    st->mu = mu; st->nu = nu;

    if (mode < N_ITER) {
      // solve (H + mu I) d = -g ; SPD -> unpivoted Gauss, fully unrolled
      float A[6][7];
      int c21b = 0;
      #pragma unroll
      for (int a = 0; a < 6; a++)
        #pragma unroll
        for (int b = a; b < 6; b++) { A[a][b] = st->H[c21b]; A[b][a] = st->H[c21b]; c21b++; }
      #pragma unroll
      for (int a = 0; a < 6; a++) { A[a][a] += mu; A[a][6] = -st->g[a]; }
      #pragma unroll
      for (int col = 0; col < 6; col++) {
        float inv = 1.f / A[col][col];
        #pragma unroll
        for (int rI = 0; rI < 6; rI++) {
          if (rI > col) {
            float f = A[rI][col] * inv;
            #pragma unroll
            for (int cc = 0; cc < 7; cc++)
              if (cc >= col) A[rI][cc] -= f * A[col][cc];
          }
        }
      }
      float d[6];
      #pragma unroll
      for (int rI = 5; rI >= 0; rI--) {
        float s = A[rI][6];
        #pragma unroll
        for (int cc = 0; cc < 6; cc++)
          if (cc > rI) s -= A[rI][cc] * d[cc];
        d[rI] = s / A[rI][rI];
      }
      float Rn[9], tn[3];
      #pragma unroll
      for (int k = 0; k < 6; k++) { st->dx[k] = d[k]; st->xc[k] = st->x[k] + d[k]; }
      se3_exp_rt(st->xc, Rn, tn);
      #pragma unroll
      for (int k = 0; k < 9; k++) st->Rc[k] = Rn[k];
      #pragma unroll
      for (int k = 0; k < 3; k++) st->tc[k] = tn[k];
    } else {
      float Rn[9], tn[3];
      se3_exp_rt(st->x, Rn, tn);
      out[0] = Rn[0]; out[1] = Rn[1]; out[2]  = Rn[2]; out[3]  = tn[0];
      out[4] = Rn[3]; out[5] = Rn[4]; out[6]  = Rn[5]; out[7]  = tn[1];
      out[8] = Rn[6]; out[9] = Rn[7]; out[10] = Rn[8]; out[11] = tn[2];
      out[12] = 0.f; out[13] = 0.f; out[14] = 0.f; out[15] = 1.f;
      out[16] = st->F / (float)N_PTS;
    }
  }
}

extern "C" void kernel_launch(void* const* d_in, const int* in_sizes, int n_in,
                              void* d_out, int out_size, void* d_ws, size_t ws_size,
                              hipStream_t stream) {
  const float* ref = (const float*)d_in[0];
  const float* trg = (const float*)d_in[1];
  const float* nrm = (const float*)d_in[2];
  float* out = (float*)d_out;

  char* ws = (char*)d_ws;
  unsigned* count      = (unsigned*)(ws);                       // 442,368 B
  unsigned* gridPacked = (unsigned*)(ws + 442368);              // 442,368 B
  unsigned* cursor     = (unsigned*)(ws + 884736);              // 442,368 B
  unsigned* blockSums  = (unsigned*)(ws + 1327104);             // 2,048 B
  float4*   sortedPts  = (float4*)  (ws + 1329152);             // 262,144 B
  unsigned* sortedIdx  = (unsigned*)(ws + 1591296);             // 65,536 B
  double*   partials   = (double*)  (ws + 1656832);             // 229,376 B
  unsigned* counter    = (unsigned*)(ws + 1886208);
  State*    st         = (State*)   (ws + 1886272);

  // build grid over targets (once) + init LM state
  zero_kernel   <<<(NCELLS + 255) / 256, 256, 0, stream>>>(count, counter, st);
  count_kernel  <<<N_PTS / 256, 256, 0, stream>>>(trg, count);
  scan1_kernel  <<<NSCAN, 256, 0, stream>>>(count, cursor, blockSums);
  scan2_kernel  <<<1, 512, 0, stream>>>(blockSums);
  scan3_kernel  <<<NSCAN, 256, 0, stream>>>(count, cursor, blockSums, gridPacked);
  scatter_kernel<<<N_PTS / 256, 256, 0, stream>>>(trg, cursor, sortedPts, sortedIdx);

  for (int e = 0; e <= N_ITER; e++)
    eval_kernel<<<NEVAL, 256, 0, stream>>>(ref, trg, nrm, gridPacked, sortedPts,
                                           sortedIdx, st, partials, counter, out, e);
}